// Round 1
// baseline (717.378 us; speedup 1.0000x reference)
//
#include <hip/hip_runtime.h>

#define B_  128
#define C_  256
#define H_  64
#define W_  64
#define J_  17
#define HP_ 32          // n_heads * n_points
#define HW_ (H_ * W_)

__device__ __forceinline__ float bilin_sample(const float* __restrict__ featc,
                                              float gx, float gy) {
    // featc -> feat[b][c] plane (H x W). align_corners=False, zeros padding.
    float ix = (gx + 1.0f) * (0.5f * W_) - 0.5f;
    float iy = (gy + 1.0f) * (0.5f * H_) - 0.5f;
    float x0f = floorf(ix), y0f = floorf(iy);
    int x0 = (int)x0f, y0 = (int)y0f;
    int x1 = x0 + 1,  y1 = y0 + 1;
    float wx1 = ix - x0f, wx0 = 1.0f - wx1;
    float wy1 = iy - y0f, wy0 = 1.0f - wy1;
    bool vx0 = (x0 >= 0) && (x0 < W_);
    bool vx1 = (x1 >= 0) && (x1 < W_);
    bool vy0 = (y0 >= 0) && (y0 < H_);
    bool vy1 = (y1 >= 0) && (y1 < H_);
    int x0c = min(max(x0, 0), W_ - 1), x1c = min(max(x1, 0), W_ - 1);
    int y0c = min(max(y0, 0), H_ - 1), y1c = min(max(y1, 0), H_ - 1);
    float v00 = (vx0 && vy0) ? featc[y0c * W_ + x0c] : 0.0f;
    float v10 = (vx1 && vy0) ? featc[y0c * W_ + x1c] : 0.0f;
    float v01 = (vx0 && vy1) ? featc[y1c * W_ + x0c] : 0.0f;
    float v11 = (vx1 && vy1) ? featc[y1c * W_ + x1c] : 0.0f;
    return v00 * (wx0 * wy0) + v10 * (wx1 * wy0)
         + v01 * (wx0 * wy1) + v11 * (wx1 * wy1);
}

__global__ __launch_bounds__(256)
void msdks_kernel(const float* __restrict__ feat,    // [B,C,H,W]
                  const float* __restrict__ refpts,  // [B,J,2]
                  const float* __restrict__ Woff,    // [C,64]
                  const float* __restrict__ boff,    // [64]
                  const float* __restrict__ Ww,      // [C,32]
                  const float* __restrict__ bw,      // [32]
                  const float* __restrict__ Wout,    // [C,C]
                  const float* __restrict__ bout,    // [C]
                  float* __restrict__ out)           // [B,J,C]
{
    __shared__ float q_lds[C_];
    __shared__ float off_lds[2 * HP_];
    __shared__ float logit_lds[HP_];
    __shared__ float wgt_lds[HP_];
    __shared__ float gx_lds[HP_];
    __shared__ float gy_lds[HP_];
    __shared__ float acc_lds[C_];

    const int bj = blockIdx.x;
    const int b  = bj / J_;
    const int j  = bj % J_;
    const int c  = threadIdx.x;   // thread == channel

    const float rx = refpts[(b * J_ + j) * 2 + 0];
    const float ry = refpts[(b * J_ + j) * 2 + 1];

    const float* featbc = feat + (size_t)(b * C_ + c) * HW_;

    // ---- Phase A: q[b,j,c] = bilinear sample at reference point ----
    float qv = bilin_sample(featbc, rx, ry);
    q_lds[c] = qv;
    __syncthreads();

    // ---- Phase B: offsets (64 outputs) and weight logits (32 outputs) ----
    if (c < 64) {
        float s = boff[c];
        #pragma unroll 4
        for (int k = 0; k < C_; ++k) s += q_lds[k] * Woff[k * 64 + c];
        off_lds[c] = s;
    } else if (c < 96) {
        const int p = c - 64;
        float s = bw[p];
        #pragma unroll 4
        for (int k = 0; k < C_; ++k) s += q_lds[k] * Ww[k * HP_ + p];
        logit_lds[p] = s;
    }
    __syncthreads();

    // ---- Phase C: softmax over HP + build clipped grid ----
    if (c < HP_) {
        float l = logit_lds[c];
        float m = l;
        for (int mask = 16; mask; mask >>= 1) m = fmaxf(m, __shfl_xor(m, mask));
        float e = expf(l - m);
        float s = e;
        for (int mask = 16; mask; mask >>= 1) s += __shfl_xor(s, mask);
        wgt_lds[c] = e / s;
        float gx = rx + off_lds[c * 2 + 0];
        float gy = ry + off_lds[c * 2 + 1];
        gx_lds[c] = fminf(fmaxf(gx, -1.0f), 1.0f);
        gy_lds[c] = fminf(fmaxf(gy, -1.0f), 1.0f);
    }
    __syncthreads();

    // ---- Phase D: gather-sample 32 points, weighted accumulate ----
    float acc = 0.0f;
    #pragma unroll 4
    for (int p = 0; p < HP_; ++p) {
        float v = bilin_sample(featbc, gx_lds[p], gy_lds[p]);
        acc += wgt_lds[p] * v;
    }
    acc_lds[c] = acc;
    __syncthreads();

    // ---- Phase E: output projection out = acc @ Wout + bout ----
    float o = bout[c];
    #pragma unroll 4
    for (int k = 0; k < C_; ++k) o += acc_lds[k] * Wout[k * C_ + c];
    out[(size_t)(b * J_ + j) * C_ + c] = o;
}

extern "C" void kernel_launch(void* const* d_in, const int* in_sizes, int n_in,
                              void* d_out, int out_size, void* d_ws, size_t ws_size,
                              hipStream_t stream) {
    const float* feat   = (const float*)d_in[0];
    const float* refpts = (const float*)d_in[1];
    const float* Woff   = (const float*)d_in[2];
    const float* boff   = (const float*)d_in[3];
    const float* Ww     = (const float*)d_in[4];
    const float* bw     = (const float*)d_in[5];
    const float* Wout   = (const float*)d_in[6];
    const float* bout   = (const float*)d_in[7];
    float* out = (float*)d_out;

    dim3 grid(B_ * J_);
    dim3 block(256);
    msdks_kernel<<<grid, block, 0, stream>>>(feat, refpts, Woff, boff, Ww, bw,
                                             Wout, bout, out);
}

// Round 2
// 314.853 us; speedup vs baseline: 2.2785x; 2.2785x over previous
//
#include <hip/hip_runtime.h>

#define B_  128
#define C_  256
#define H_  64
#define W_  64
#define J_  17
#define HP_ 32          // n_heads * n_points
#define HW_ (H_ * W_)

// ---------------------------------------------------------------------------
// Transpose feat [B,C,H,W] -> featT [B,HW,C] so gathers are channel-contiguous
// ---------------------------------------------------------------------------
__global__ __launch_bounds__(256)
void transpose_kernel(const float* __restrict__ feat, float* __restrict__ featT) {
    __shared__ float tile[64][65];  // +1 pad: conflict-free column reads
    const int blk  = blockIdx.x;
    const int c_t  = blk & 3;            // 4 channel tiles of 64
    const int hw_t = (blk >> 2) & 63;    // 64 hw tiles of 64
    const int b    = blk >> 8;
    const int c0   = c_t * 64;
    const int hw0  = hw_t * 64;
    const int t    = threadIdx.x;
    const int lc   = t & 63;   // 0..63
    const int lr   = t >> 6;   // 0..3

    const float* src = feat + (size_t)(b * C_ + c0) * HW_ + hw0;
    #pragma unroll
    for (int cc = 0; cc < 64; cc += 4)
        tile[cc + lr][lc] = src[(size_t)(cc + lr) * HW_ + lc];
    __syncthreads();
    float* dst = featT + ((size_t)b * HW_ + hw0) * C_ + c0;
    #pragma unroll
    for (int hh = 0; hh < 64; hh += 4)
        dst[(size_t)(hh + lr) * C_ + lc] = tile[lc][hh + lr];
}

// ---------------------------------------------------------------------------
// Bilinear sample helpers
// ---------------------------------------------------------------------------
__device__ __forceinline__ float bilin_sample_T(const float* __restrict__ featTb,
                                                int c, float gx, float gy) {
    // featTb -> featT[b], layout [HW][C]. align_corners=False, zeros padding.
    float ix = (gx + 1.0f) * (0.5f * W_) - 0.5f;
    float iy = (gy + 1.0f) * (0.5f * H_) - 0.5f;
    float x0f = floorf(ix), y0f = floorf(iy);
    int x0 = (int)x0f, y0 = (int)y0f;
    int x1 = x0 + 1,  y1 = y0 + 1;
    float wx1 = ix - x0f, wx0 = 1.0f - wx1;
    float wy1 = iy - y0f, wy0 = 1.0f - wy1;
    bool vx0 = (x0 >= 0) && (x0 < W_);
    bool vx1 = (x1 >= 0) && (x1 < W_);
    bool vy0 = (y0 >= 0) && (y0 < H_);
    bool vy1 = (y1 >= 0) && (y1 < H_);
    int x0c = min(max(x0, 0), W_ - 1), x1c = min(max(x1, 0), W_ - 1);
    int y0c = min(max(y0, 0), H_ - 1), y1c = min(max(y1, 0), H_ - 1);
    float v00 = (vx0 && vy0) ? featTb[(size_t)(y0c * W_ + x0c) * C_ + c] : 0.0f;
    float v10 = (vx1 && vy0) ? featTb[(size_t)(y0c * W_ + x1c) * C_ + c] : 0.0f;
    float v01 = (vx0 && vy1) ? featTb[(size_t)(y1c * W_ + x0c) * C_ + c] : 0.0f;
    float v11 = (vx1 && vy1) ? featTb[(size_t)(y1c * W_ + x1c) * C_ + c] : 0.0f;
    return v00 * (wx0 * wy0) + v10 * (wx1 * wy0)
         + v01 * (wx0 * wy1) + v11 * (wx1 * wy1);
}

__device__ __forceinline__ float bilin_sample(const float* __restrict__ featc,
                                              float gx, float gy) {
    float ix = (gx + 1.0f) * (0.5f * W_) - 0.5f;
    float iy = (gy + 1.0f) * (0.5f * H_) - 0.5f;
    float x0f = floorf(ix), y0f = floorf(iy);
    int x0 = (int)x0f, y0 = (int)y0f;
    int x1 = x0 + 1,  y1 = y0 + 1;
    float wx1 = ix - x0f, wx0 = 1.0f - wx1;
    float wy1 = iy - y0f, wy0 = 1.0f - wy1;
    bool vx0 = (x0 >= 0) && (x0 < W_);
    bool vx1 = (x1 >= 0) && (x1 < W_);
    bool vy0 = (y0 >= 0) && (y0 < H_);
    bool vy1 = (y1 >= 0) && (y1 < H_);
    int x0c = min(max(x0, 0), W_ - 1), x1c = min(max(x1, 0), W_ - 1);
    int y0c = min(max(y0, 0), H_ - 1), y1c = min(max(y1, 0), H_ - 1);
    float v00 = (vx0 && vy0) ? featc[y0c * W_ + x0c] : 0.0f;
    float v10 = (vx1 && vy0) ? featc[y0c * W_ + x1c] : 0.0f;
    float v01 = (vx0 && vy1) ? featc[y1c * W_ + x0c] : 0.0f;
    float v11 = (vx1 && vy1) ? featc[y1c * W_ + x1c] : 0.0f;
    return v00 * (wx0 * wy0) + v10 * (wx1 * wy0)
         + v01 * (wx0 * wy1) + v11 * (wx1 * wy1);
}

// ---------------------------------------------------------------------------
// Main sampler using transposed features
// ---------------------------------------------------------------------------
__global__ __launch_bounds__(256)
void msdks_kernel_T(const float* __restrict__ featT,   // [B,HW,C]
                    const float* __restrict__ refpts,  // [B,J,2]
                    const float* __restrict__ Woff,    // [C,64]
                    const float* __restrict__ boff,    // [64]
                    const float* __restrict__ Ww,      // [C,32]
                    const float* __restrict__ bw,      // [32]
                    const float* __restrict__ Wout,    // [C,C]
                    const float* __restrict__ bout,    // [C]
                    float* __restrict__ out)           // [B,J,C]
{
    __shared__ float q_lds[C_];
    __shared__ float off_lds[2 * HP_];
    __shared__ float logit_lds[HP_];
    __shared__ float wgt_lds[HP_];
    __shared__ float gx_lds[HP_];
    __shared__ float gy_lds[HP_];
    __shared__ float acc_lds[C_];

    const int bj = blockIdx.x;
    const int b  = bj / J_;
    const int j  = bj % J_;
    const int c  = threadIdx.x;   // thread == channel

    const float rx = refpts[(b * J_ + j) * 2 + 0];
    const float ry = refpts[(b * J_ + j) * 2 + 1];

    const float* featTb = featT + (size_t)b * HW_ * C_;

    // ---- Phase A: q[b,j,c] = bilinear sample at reference point ----
    float qv = bilin_sample_T(featTb, c, rx, ry);
    q_lds[c] = qv;
    __syncthreads();

    // ---- Phase B: offsets (64 outputs) and weight logits (32 outputs) ----
    if (c < 64) {
        float s = boff[c];
        #pragma unroll 4
        for (int k = 0; k < C_; ++k) s += q_lds[k] * Woff[k * 64 + c];
        off_lds[c] = s;
    } else if (c < 96) {
        const int p = c - 64;
        float s = bw[p];
        #pragma unroll 4
        for (int k = 0; k < C_; ++k) s += q_lds[k] * Ww[k * HP_ + p];
        logit_lds[p] = s;
    }
    __syncthreads();

    // ---- Phase C: softmax over HP + build clipped grid ----
    if (c < HP_) {
        float l = logit_lds[c];
        float m = l;
        for (int mask = 16; mask; mask >>= 1) m = fmaxf(m, __shfl_xor(m, mask));
        float e = expf(l - m);
        float s = e;
        for (int mask = 16; mask; mask >>= 1) s += __shfl_xor(s, mask);
        wgt_lds[c] = e / s;
        float gx = rx + off_lds[c * 2 + 0];
        float gy = ry + off_lds[c * 2 + 1];
        gx_lds[c] = fminf(fmaxf(gx, -1.0f), 1.0f);
        gy_lds[c] = fminf(fmaxf(gy, -1.0f), 1.0f);
    }
    __syncthreads();

    // ---- Phase D: gather-sample 32 points, weighted accumulate ----
    float acc = 0.0f;
    #pragma unroll 4
    for (int p = 0; p < HP_; ++p) {
        float v = bilin_sample_T(featTb, c, gx_lds[p], gy_lds[p]);
        acc += wgt_lds[p] * v;
    }
    acc_lds[c] = acc;
    __syncthreads();

    // ---- Phase E: output projection out = acc @ Wout + bout ----
    float o = bout[c];
    #pragma unroll 4
    for (int k = 0; k < C_; ++k) o += acc_lds[k] * Wout[k * C_ + c];
    out[(size_t)(b * J_ + j) * C_ + c] = o;
}

// ---------------------------------------------------------------------------
// Fallback (no-workspace) kernel: original layout
// ---------------------------------------------------------------------------
__global__ __launch_bounds__(256)
void msdks_kernel(const float* __restrict__ feat,
                  const float* __restrict__ refpts,
                  const float* __restrict__ Woff,
                  const float* __restrict__ boff,
                  const float* __restrict__ Ww,
                  const float* __restrict__ bw,
                  const float* __restrict__ Wout,
                  const float* __restrict__ bout,
                  float* __restrict__ out)
{
    __shared__ float q_lds[C_];
    __shared__ float off_lds[2 * HP_];
    __shared__ float logit_lds[HP_];
    __shared__ float wgt_lds[HP_];
    __shared__ float gx_lds[HP_];
    __shared__ float gy_lds[HP_];
    __shared__ float acc_lds[C_];

    const int bj = blockIdx.x;
    const int b  = bj / J_;
    const int j  = bj % J_;
    const int c  = threadIdx.x;

    const float rx = refpts[(b * J_ + j) * 2 + 0];
    const float ry = refpts[(b * J_ + j) * 2 + 1];
    const float* featbc = feat + (size_t)(b * C_ + c) * HW_;

    float qv = bilin_sample(featbc, rx, ry);
    q_lds[c] = qv;
    __syncthreads();

    if (c < 64) {
        float s = boff[c];
        for (int k = 0; k < C_; ++k) s += q_lds[k] * Woff[k * 64 + c];
        off_lds[c] = s;
    } else if (c < 96) {
        const int p = c - 64;
        float s = bw[p];
        for (int k = 0; k < C_; ++k) s += q_lds[k] * Ww[k * HP_ + p];
        logit_lds[p] = s;
    }
    __syncthreads();

    if (c < HP_) {
        float l = logit_lds[c];
        float m = l;
        for (int mask = 16; mask; mask >>= 1) m = fmaxf(m, __shfl_xor(m, mask));
        float e = expf(l - m);
        float s = e;
        for (int mask = 16; mask; mask >>= 1) s += __shfl_xor(s, mask);
        wgt_lds[c] = e / s;
        float gx = rx + off_lds[c * 2 + 0];
        float gy = ry + off_lds[c * 2 + 1];
        gx_lds[c] = fminf(fmaxf(gx, -1.0f), 1.0f);
        gy_lds[c] = fminf(fmaxf(gy, -1.0f), 1.0f);
    }
    __syncthreads();

    float acc = 0.0f;
    for (int p = 0; p < HP_; ++p) {
        float v = bilin_sample(featbc, gx_lds[p], gy_lds[p]);
        acc += wgt_lds[p] * v;
    }
    acc_lds[c] = acc;
    __syncthreads();

    float o = bout[c];
    for (int k = 0; k < C_; ++k) o += acc_lds[k] * Wout[k * C_ + c];
    out[(size_t)(b * J_ + j) * C_ + c] = o;
}

extern "C" void kernel_launch(void* const* d_in, const int* in_sizes, int n_in,
                              void* d_out, int out_size, void* d_ws, size_t ws_size,
                              hipStream_t stream) {
    const float* feat   = (const float*)d_in[0];
    const float* refpts = (const float*)d_in[1];
    const float* Woff   = (const float*)d_in[2];
    const float* boff   = (const float*)d_in[3];
    const float* Ww     = (const float*)d_in[4];
    const float* bw     = (const float*)d_in[5];
    const float* Wout   = (const float*)d_in[6];
    const float* bout   = (const float*)d_in[7];
    float* out = (float*)d_out;

    const size_t featT_bytes = (size_t)B_ * HW_ * C_ * sizeof(float);

    if (ws_size >= featT_bytes) {
        float* featT = (float*)d_ws;
        transpose_kernel<<<dim3(B_ * 64 * 4), dim3(256), 0, stream>>>(feat, featT);
        msdks_kernel_T<<<dim3(B_ * J_), dim3(256), 0, stream>>>(featT, refpts, Woff,
                                                                boff, Ww, bw, Wout,
                                                                bout, out);
    } else {
        msdks_kernel<<<dim3(B_ * J_), dim3(256), 0, stream>>>(feat, refpts, Woff,
                                                              boff, Ww, bw, Wout,
                                                              bout, out);
    }
}

// Round 3
// 191.602 us; speedup vs baseline: 3.7441x; 1.6433x over previous
//
#include <hip/hip_runtime.h>

#define B_  128
#define C_  256
#define H_  64
#define W_  64
#define J_  17
#define HP_ 32          // n_heads * n_points
#define HW_ (H_ * W_)
#define CG_ 4           // channels per gather block

// ---------------------------------------------------------------------------
// Pass 1+2: per (b,j) — sample q at ref point (scattered reads, small volume),
// GEMVs for offsets/logits, softmax, emit per-(b,j,p) corner metadata:
// 4 clamped flat indices + 4 fused weights (bilinear * valid * softmax_w).
// ---------------------------------------------------------------------------
__global__ __launch_bounds__(256)
void pass12_kernel(const float* __restrict__ feat,    // [B,C,H,W]
                   const float* __restrict__ refpts,  // [B,J,2]
                   const float* __restrict__ Woff,    // [C,64]
                   const float* __restrict__ boff,    // [64]
                   const float* __restrict__ Ww,      // [C,32]
                   const float* __restrict__ bw,      // [32]
                   int4*  __restrict__ meta_idx,      // [B*J*HP]
                   float4* __restrict__ meta_w)       // [B*J*HP]
{
    __shared__ float q_lds[C_];
    __shared__ float off_lds[2 * HP_];

    const int bj = blockIdx.x;
    const int b  = bj / J_;
    const int j  = bj % J_;
    const int c  = threadIdx.x;

    const float rx = refpts[(b * J_ + j) * 2 + 0];
    const float ry = refpts[(b * J_ + j) * 2 + 1];

    // ---- q sample (channel-strided; only ~68 pixels/batch total) ----
    {
        const float* featbc = feat + (size_t)(b * C_ + c) * HW_;
        float ix = (rx + 1.0f) * (0.5f * W_) - 0.5f;
        float iy = (ry + 1.0f) * (0.5f * H_) - 0.5f;
        float x0f = floorf(ix), y0f = floorf(iy);
        int x0 = (int)x0f, y0 = (int)y0f;
        int x1 = x0 + 1,  y1 = y0 + 1;
        float wx1 = ix - x0f, wx0 = 1.0f - wx1;
        float wy1 = iy - y0f, wy0 = 1.0f - wy1;
        bool vx0 = (x0 >= 0) && (x0 < W_);
        bool vx1 = (x1 >= 0) && (x1 < W_);
        bool vy0 = (y0 >= 0) && (y0 < H_);
        bool vy1 = (y1 >= 0) && (y1 < H_);
        int x0c = min(max(x0, 0), W_ - 1), x1c = min(max(x1, 0), W_ - 1);
        int y0c = min(max(y0, 0), H_ - 1), y1c = min(max(y1, 0), H_ - 1);
        float v00 = (vx0 && vy0) ? featbc[y0c * W_ + x0c] : 0.0f;
        float v10 = (vx1 && vy0) ? featbc[y0c * W_ + x1c] : 0.0f;
        float v01 = (vx0 && vy1) ? featbc[y1c * W_ + x0c] : 0.0f;
        float v11 = (vx1 && vy1) ? featbc[y1c * W_ + x1c] : 0.0f;
        q_lds[c] = v00 * (wx0 * wy0) + v10 * (wx1 * wy0)
                 + v01 * (wx0 * wy1) + v11 * (wx1 * wy1);
    }
    __syncthreads();

    // ---- GEMVs ----
    __shared__ float logit_lds[HP_];
    if (c < 64) {
        float s = boff[c];
        #pragma unroll 4
        for (int k = 0; k < C_; ++k) s += q_lds[k] * Woff[k * 64 + c];
        off_lds[c] = s;
    } else if (c < 96) {
        const int p = c - 64;
        float s = bw[p];
        #pragma unroll 4
        for (int k = 0; k < C_; ++k) s += q_lds[k] * Ww[k * HP_ + p];
        logit_lds[p] = s;
    }
    __syncthreads();

    // ---- softmax + grid + corner metadata ----
    if (c < HP_) {
        float l = logit_lds[c];
        float m = l;
        #pragma unroll
        for (int mask = 16; mask >= 1; mask >>= 1) m = fmaxf(m, __shfl_xor(m, mask));
        float e = expf(l - m);
        float s = e;
        #pragma unroll
        for (int mask = 16; mask >= 1; mask >>= 1) s += __shfl_xor(s, mask);
        const float ww = e / s;

        float gx = fminf(fmaxf(rx + off_lds[2 * c + 0], -1.0f), 1.0f);
        float gy = fminf(fmaxf(ry + off_lds[2 * c + 1], -1.0f), 1.0f);
        float ix = (gx + 1.0f) * (0.5f * W_) - 0.5f;
        float iy = (gy + 1.0f) * (0.5f * H_) - 0.5f;
        float x0f = floorf(ix), y0f = floorf(iy);
        int x0 = (int)x0f, y0 = (int)y0f;
        int x1 = x0 + 1,  y1 = y0 + 1;
        float wx1 = ix - x0f, wx0 = 1.0f - wx1;
        float wy1 = iy - y0f, wy0 = 1.0f - wy1;
        float v00 = (float)((x0 >= 0) && (x0 < W_) && (y0 >= 0) && (y0 < H_));
        float v10 = (float)((x1 >= 0) && (x1 < W_) && (y0 >= 0) && (y0 < H_));
        float v01 = (float)((x0 >= 0) && (x0 < W_) && (y1 >= 0) && (y1 < H_));
        float v11 = (float)((x1 >= 0) && (x1 < W_) && (y1 >= 0) && (y1 < H_));
        int x0c = min(max(x0, 0), W_ - 1), x1c = min(max(x1, 0), W_ - 1);
        int y0c = min(max(y0, 0), H_ - 1), y1c = min(max(y1, 0), H_ - 1);
        const int mi = bj * HP_ + c;
        meta_idx[mi] = make_int4(y0c * W_ + x0c, y0c * W_ + x1c,
                                 y1c * W_ + x0c, y1c * W_ + x1c);
        meta_w[mi] = make_float4(ww * wx0 * wy0 * v00, ww * wx1 * wy0 * v10,
                                 ww * wx0 * wy1 * v01, ww * wx1 * wy1 * v11);
    }
}

// ---------------------------------------------------------------------------
// Pass 3: per (b, 4-channel group) — stream 4 planes coalesced into LDS once,
// resolve all (j,p) gathers from LDS, reduce over p via shuffles.
// ---------------------------------------------------------------------------
__global__ __launch_bounds__(256)
void gather_kernel(const float* __restrict__ feat,      // [B,C,H,W]
                   const int4*  __restrict__ meta_idx,  // [B*J*HP]
                   const float4* __restrict__ meta_w,   // [B*J*HP]
                   float* __restrict__ acc)             // [B,J,C]
{
    __shared__ float plane[CG_ * HW_];   // 64 KB

    const int blk = blockIdx.x;
    const int b   = blk >> 6;       // / (C_/CG_)
    const int cg  = blk & 63;
    const int c0  = cg * CG_;
    const int t   = threadIdx.x;

    // coalesced load of 4 planes (16 KB each)
    #pragma unroll
    for (int k = 0; k < CG_; ++k) {
        const float4* src = (const float4*)(feat + (size_t)(b * C_ + c0 + k) * HW_);
        float4* dst = (float4*)(plane + k * HW_);
        #pragma unroll
        for (int i = 0; i < 4; ++i)
            dst[t + i * 256] = src[t + i * 256];
    }
    __syncthreads();

    const int wv   = t >> 6;        // wave 0..3
    const int ln   = t & 63;
    const int p    = ln & 31;
    const int half = ln >> 5;

    #pragma unroll
    for (int iter = 0; iter < 3; ++iter) {
        const int j = iter * 8 + wv * 2 + half;
        float pj0 = 0.0f, pj1 = 0.0f, pj2 = 0.0f, pj3 = 0.0f;
        if (j < J_) {
            const int mi = (b * J_ + j) * HP_ + p;
            const int4   id = meta_idx[mi];
            const float4 w  = meta_w[mi];
            pj0 = w.x * plane[0 * HW_ + id.x] + w.y * plane[0 * HW_ + id.y]
                + w.z * plane[0 * HW_ + id.z] + w.w * plane[0 * HW_ + id.w];
            pj1 = w.x * plane[1 * HW_ + id.x] + w.y * plane[1 * HW_ + id.y]
                + w.z * plane[1 * HW_ + id.z] + w.w * plane[1 * HW_ + id.w];
            pj2 = w.x * plane[2 * HW_ + id.x] + w.y * plane[2 * HW_ + id.y]
                + w.z * plane[2 * HW_ + id.z] + w.w * plane[2 * HW_ + id.w];
            pj3 = w.x * plane[3 * HW_ + id.x] + w.y * plane[3 * HW_ + id.y]
                + w.z * plane[3 * HW_ + id.z] + w.w * plane[3 * HW_ + id.w];
        }
        #pragma unroll
        for (int mask = 16; mask >= 1; mask >>= 1) {
            pj0 += __shfl_xor(pj0, mask);
            pj1 += __shfl_xor(pj1, mask);
            pj2 += __shfl_xor(pj2, mask);
            pj3 += __shfl_xor(pj3, mask);
        }
        if (j < J_ && p == 0) {
            float4* dst = (float4*)(acc + ((size_t)(b * J_ + j)) * C_ + c0);
            *dst = make_float4(pj0, pj1, pj2, pj3);
        }
    }
}

// ---------------------------------------------------------------------------
// Pass 4: output projection out[bj,:] = acc[bj,:] @ Wout + bout
// ---------------------------------------------------------------------------
__global__ __launch_bounds__(256)
void proj_kernel(const float* __restrict__ acc,   // [B*J, C]
                 const float* __restrict__ Wout,  // [C, C]
                 const float* __restrict__ bout,  // [C]
                 float* __restrict__ out)         // [B*J, C]
{
    __shared__ float a_lds[C_];
    const int bj = blockIdx.x;
    const int c  = threadIdx.x;
    a_lds[c] = acc[(size_t)bj * C_ + c];
    __syncthreads();
    float o = bout[c];
    #pragma unroll 4
    for (int k = 0; k < C_; ++k) o += a_lds[k] * Wout[k * C_ + c];
    out[(size_t)bj * C_ + c] = o;
}

// ---------------------------------------------------------------------------
// Fallback (no/small workspace): monolithic original-layout kernel
// ---------------------------------------------------------------------------
__device__ __forceinline__ float bilin_sample(const float* __restrict__ featc,
                                              float gx, float gy) {
    float ix = (gx + 1.0f) * (0.5f * W_) - 0.5f;
    float iy = (gy + 1.0f) * (0.5f * H_) - 0.5f;
    float x0f = floorf(ix), y0f = floorf(iy);
    int x0 = (int)x0f, y0 = (int)y0f;
    int x1 = x0 + 1,  y1 = y0 + 1;
    float wx1 = ix - x0f, wx0 = 1.0f - wx1;
    float wy1 = iy - y0f, wy0 = 1.0f - wy1;
    bool vx0 = (x0 >= 0) && (x0 < W_);
    bool vx1 = (x1 >= 0) && (x1 < W_);
    bool vy0 = (y0 >= 0) && (y0 < H_);
    bool vy1 = (y1 >= 0) && (y1 < H_);
    int x0c = min(max(x0, 0), W_ - 1), x1c = min(max(x1, 0), W_ - 1);
    int y0c = min(max(y0, 0), H_ - 1), y1c = min(max(y1, 0), H_ - 1);
    float v00 = (vx0 && vy0) ? featc[y0c * W_ + x0c] : 0.0f;
    float v10 = (vx1 && vy0) ? featc[y0c * W_ + x1c] : 0.0f;
    float v01 = (vx0 && vy1) ? featc[y1c * W_ + x0c] : 0.0f;
    float v11 = (vx1 && vy1) ? featc[y1c * W_ + x1c] : 0.0f;
    return v00 * (wx0 * wy0) + v10 * (wx1 * wy0)
         + v01 * (wx0 * wy1) + v11 * (wx1 * wy1);
}

__global__ __launch_bounds__(256)
void msdks_kernel(const float* __restrict__ feat,
                  const float* __restrict__ refpts,
                  const float* __restrict__ Woff,
                  const float* __restrict__ boff,
                  const float* __restrict__ Ww,
                  const float* __restrict__ bw,
                  const float* __restrict__ Wout,
                  const float* __restrict__ bout,
                  float* __restrict__ out)
{
    __shared__ float q_lds[C_];
    __shared__ float off_lds[2 * HP_];
    __shared__ float logit_lds[HP_];
    __shared__ float wgt_lds[HP_];
    __shared__ float gx_lds[HP_];
    __shared__ float gy_lds[HP_];
    __shared__ float acc_lds[C_];

    const int bj = blockIdx.x;
    const int b  = bj / J_;
    const int j  = bj % J_;
    const int c  = threadIdx.x;

    const float rx = refpts[(b * J_ + j) * 2 + 0];
    const float ry = refpts[(b * J_ + j) * 2 + 1];
    const float* featbc = feat + (size_t)(b * C_ + c) * HW_;

    q_lds[c] = bilin_sample(featbc, rx, ry);
    __syncthreads();

    if (c < 64) {
        float s = boff[c];
        for (int k = 0; k < C_; ++k) s += q_lds[k] * Woff[k * 64 + c];
        off_lds[c] = s;
    } else if (c < 96) {
        const int p = c - 64;
        float s = bw[p];
        for (int k = 0; k < C_; ++k) s += q_lds[k] * Ww[k * HP_ + p];
        logit_lds[p] = s;
    }
    __syncthreads();

    if (c < HP_) {
        float l = logit_lds[c];
        float m = l;
        for (int mask = 16; mask; mask >>= 1) m = fmaxf(m, __shfl_xor(m, mask));
        float e = expf(l - m);
        float s = e;
        for (int mask = 16; mask; mask >>= 1) s += __shfl_xor(s, mask);
        wgt_lds[c] = e / s;
        gx_lds[c] = fminf(fmaxf(rx + off_lds[c * 2 + 0], -1.0f), 1.0f);
        gy_lds[c] = fminf(fmaxf(ry + off_lds[c * 2 + 1], -1.0f), 1.0f);
    }
    __syncthreads();

    float acc = 0.0f;
    for (int pp = 0; pp < HP_; ++pp)
        acc += wgt_lds[pp] * bilin_sample(featbc, gx_lds[pp], gy_lds[pp]);
    acc_lds[c] = acc;
    __syncthreads();

    float o = bout[c];
    for (int k = 0; k < C_; ++k) o += acc_lds[k] * Wout[k * C_ + c];
    out[(size_t)(b * J_ + j) * C_ + c] = o;
}

extern "C" void kernel_launch(void* const* d_in, const int* in_sizes, int n_in,
                              void* d_out, int out_size, void* d_ws, size_t ws_size,
                              hipStream_t stream) {
    const float* feat   = (const float*)d_in[0];
    const float* refpts = (const float*)d_in[1];
    const float* Woff   = (const float*)d_in[2];
    const float* boff   = (const float*)d_in[3];
    const float* Ww     = (const float*)d_in[4];
    const float* bw     = (const float*)d_in[5];
    const float* Wout   = (const float*)d_in[6];
    const float* bout   = (const float*)d_in[7];
    float* out = (float*)d_out;

    const size_t n_meta    = (size_t)B_ * J_ * HP_;          // 69632
    const size_t idx_bytes = n_meta * sizeof(int4);          // 1.11 MB
    const size_t w_bytes   = n_meta * sizeof(float4);        // 1.11 MB
    const size_t acc_bytes = (size_t)B_ * J_ * C_ * sizeof(float); // 2.23 MB

    if (ws_size >= idx_bytes + w_bytes + acc_bytes) {
        char* ws = (char*)d_ws;
        int4*   meta_idx = (int4*)ws;
        float4* meta_w   = (float4*)(ws + idx_bytes);
        float*  acc      = (float*)(ws + idx_bytes + w_bytes);

        pass12_kernel<<<dim3(B_ * J_), dim3(256), 0, stream>>>(
            feat, refpts, Woff, boff, Ww, bw, meta_idx, meta_w);
        gather_kernel<<<dim3(B_ * (C_ / CG_)), dim3(256), 0, stream>>>(
            feat, meta_idx, meta_w, acc);
        proj_kernel<<<dim3(B_ * J_), dim3(256), 0, stream>>>(
            acc, Wout, bout, out);
    } else {
        msdks_kernel<<<dim3(B_ * J_), dim3(256), 0, stream>>>(
            feat, refpts, Woff, boff, Ww, bw, Wout, bout, out);
    }
}

// Round 4
// 177.458 us; speedup vs baseline: 4.0425x; 1.0797x over previous
//
#include <hip/hip_runtime.h>

#define B_  128
#define C_  256
#define H_  64
#define W_  64
#define J_  17
#define HP_ 32          // n_heads * n_points
#define HW_ (H_ * W_)
#define CG_ 2           // channels per gather block (32 KB LDS -> 5 blocks/CU)

// ---------------------------------------------------------------------------
// Pass 1+2: per (b,j) — sample q at ref point, k-split GEMVs for
// offsets/logits, softmax, emit per-(b,j,p) corner metadata.
// ---------------------------------------------------------------------------
__global__ __launch_bounds__(256)
void pass12_kernel(const float* __restrict__ feat,    // [B,C,H,W]
                   const float* __restrict__ refpts,  // [B,J,2]
                   const float* __restrict__ Woff,    // [C,64]
                   const float* __restrict__ boff,    // [64]
                   const float* __restrict__ Ww,      // [C,32]
                   const float* __restrict__ bw,      // [32]
                   int4*  __restrict__ meta_idx,      // [B*J*HP]
                   float4* __restrict__ meta_w)       // [B*J*HP]
{
    __shared__ float q_lds[C_];
    __shared__ float part_off[4][64];
    __shared__ float part_w[4][32];
    __shared__ float off_lds[2 * HP_];
    __shared__ float logit_lds[HP_];

    const int bj = blockIdx.x;
    const int b  = bj / J_;
    const int j  = bj % J_;
    const int c  = threadIdx.x;

    const float rx = refpts[(b * J_ + j) * 2 + 0];
    const float ry = refpts[(b * J_ + j) * 2 + 1];

    // ---- q sample (channel-strided; small volume) ----
    {
        const float* featbc = feat + (size_t)(b * C_ + c) * HW_;
        float ix = (rx + 1.0f) * (0.5f * W_) - 0.5f;
        float iy = (ry + 1.0f) * (0.5f * H_) - 0.5f;
        float x0f = floorf(ix), y0f = floorf(iy);
        int x0 = (int)x0f, y0 = (int)y0f;
        int x1 = x0 + 1,  y1 = y0 + 1;
        float wx1 = ix - x0f, wx0 = 1.0f - wx1;
        float wy1 = iy - y0f, wy0 = 1.0f - wy1;
        bool vx0 = (x0 >= 0) && (x0 < W_);
        bool vx1 = (x1 >= 0) && (x1 < W_);
        bool vy0 = (y0 >= 0) && (y0 < H_);
        bool vy1 = (y1 >= 0) && (y1 < H_);
        int x0c = min(max(x0, 0), W_ - 1), x1c = min(max(x1, 0), W_ - 1);
        int y0c = min(max(y0, 0), H_ - 1), y1c = min(max(y1, 0), H_ - 1);
        float v00 = (vx0 && vy0) ? featbc[y0c * W_ + x0c] : 0.0f;
        float v10 = (vx1 && vy0) ? featbc[y0c * W_ + x1c] : 0.0f;
        float v01 = (vx0 && vy1) ? featbc[y1c * W_ + x0c] : 0.0f;
        float v11 = (vx1 && vy1) ? featbc[y1c * W_ + x1c] : 0.0f;
        q_lds[c] = v00 * (wx0 * wy0) + v10 * (wx1 * wy0)
                 + v01 * (wx0 * wy1) + v11 * (wx1 * wy1);
    }
    __syncthreads();

    // ---- k-split GEMVs: wave wv covers k in [64*wv, 64*wv+64) ----
    {
        const int wv = c >> 6, ln = c & 63;
        float aoff = 0.0f, aw = 0.0f;
        #pragma unroll 8
        for (int i = 0; i < 64; ++i) {
            const int k = wv * 64 + i;
            const float qv = q_lds[k];
            aoff += qv * Woff[k * 64 + ln];
            if (ln < 32) aw += qv * Ww[k * 32 + ln];
        }
        part_off[wv][ln] = aoff;
        if (ln < 32) part_w[wv][ln] = aw;
    }
    __syncthreads();
    if (c < 64) {
        off_lds[c] = boff[c] + part_off[0][c] + part_off[1][c]
                   + part_off[2][c] + part_off[3][c];
    } else if (c < 96) {
        const int p = c - 64;
        logit_lds[p] = bw[p] + part_w[0][p] + part_w[1][p]
                     + part_w[2][p] + part_w[3][p];
    }
    __syncthreads();

    // ---- softmax + grid + corner metadata ----
    if (c < HP_) {
        float l = logit_lds[c];
        float m = l;
        #pragma unroll
        for (int mask = 16; mask >= 1; mask >>= 1) m = fmaxf(m, __shfl_xor(m, mask));
        float e = expf(l - m);
        float s = e;
        #pragma unroll
        for (int mask = 16; mask >= 1; mask >>= 1) s += __shfl_xor(s, mask);
        const float ww = e / s;

        float gx = fminf(fmaxf(rx + off_lds[2 * c + 0], -1.0f), 1.0f);
        float gy = fminf(fmaxf(ry + off_lds[2 * c + 1], -1.0f), 1.0f);
        float ix = (gx + 1.0f) * (0.5f * W_) - 0.5f;
        float iy = (gy + 1.0f) * (0.5f * H_) - 0.5f;
        float x0f = floorf(ix), y0f = floorf(iy);
        int x0 = (int)x0f, y0 = (int)y0f;
        int x1 = x0 + 1,  y1 = y0 + 1;
        float wx1 = ix - x0f, wx0 = 1.0f - wx1;
        float wy1 = iy - y0f, wy0 = 1.0f - wy1;
        float v00 = (float)((x0 >= 0) && (x0 < W_) && (y0 >= 0) && (y0 < H_));
        float v10 = (float)((x1 >= 0) && (x1 < W_) && (y0 >= 0) && (y0 < H_));
        float v01 = (float)((x0 >= 0) && (x0 < W_) && (y1 >= 0) && (y1 < H_));
        float v11 = (float)((x1 >= 0) && (x1 < W_) && (y1 >= 0) && (y1 < H_));
        int x0c = min(max(x0, 0), W_ - 1), x1c = min(max(x1, 0), W_ - 1);
        int y0c = min(max(y0, 0), H_ - 1), y1c = min(max(y1, 0), H_ - 1);
        const int mi = bj * HP_ + c;
        meta_idx[mi] = make_int4(y0c * W_ + x0c, y0c * W_ + x1c,
                                 y1c * W_ + x0c, y1c * W_ + x1c);
        meta_w[mi] = make_float4(ww * wx0 * wy0 * v00, ww * wx1 * wy0 * v10,
                                 ww * wx0 * wy1 * v01, ww * wx1 * wy1 * v11);
    }
}

// ---------------------------------------------------------------------------
// Pass 3: per (b, 2-channel group) — stream 2 planes coalesced into LDS,
// resolve all (j,p) gathers from LDS, reduce over p via shuffles.
// ---------------------------------------------------------------------------
__global__ __launch_bounds__(256)
void gather_kernel(const float* __restrict__ feat,      // [B,C,H,W]
                   const int4*  __restrict__ meta_idx,  // [B*J*HP]
                   const float4* __restrict__ meta_w,   // [B*J*HP]
                   float* __restrict__ acc)             // [B,J,C]
{
    __shared__ float plane[CG_ * HW_];   // 32 KB

    const int blk = blockIdx.x;
    const int b   = blk >> 7;       // / (C_/CG_) = /128
    const int cg  = blk & 127;
    const int c0  = cg * CG_;
    const int t   = threadIdx.x;

    // coalesced load of 2 planes (2048 float4s, 8 per thread)
    {
        const float4* src = (const float4*)(feat + (size_t)(b * C_ + c0) * HW_);
        float4* dst = (float4*)plane;
        #pragma unroll
        for (int i = 0; i < 8; ++i)
            dst[t + i * 256] = src[t + i * 256];
    }
    __syncthreads();

    const int wv   = t >> 6;        // wave 0..3
    const int ln   = t & 63;
    const int p    = ln & 31;
    const int half = ln >> 5;

    #pragma unroll
    for (int iter = 0; iter < 3; ++iter) {
        const int j = iter * 8 + wv * 2 + half;
        float pj0 = 0.0f, pj1 = 0.0f;
        if (j < J_) {
            const int mi = (b * J_ + j) * HP_ + p;
            const int4   id = meta_idx[mi];
            const float4 w  = meta_w[mi];
            pj0 = w.x * plane[id.x] + w.y * plane[id.y]
                + w.z * plane[id.z] + w.w * plane[id.w];
            pj1 = w.x * plane[HW_ + id.x] + w.y * plane[HW_ + id.y]
                + w.z * plane[HW_ + id.z] + w.w * plane[HW_ + id.w];
        }
        #pragma unroll
        for (int mask = 16; mask >= 1; mask >>= 1) {
            pj0 += __shfl_xor(pj0, mask);
            pj1 += __shfl_xor(pj1, mask);
        }
        if (j < J_ && p == 0) {
            float2* dst = (float2*)(acc + ((size_t)(b * J_ + j)) * C_ + c0);
            *dst = make_float2(pj0, pj1);
        }
    }
}

// ---------------------------------------------------------------------------
// Pass 4: k-split output projection out[bj,:] = acc[bj,:] @ Wout + bout
// ---------------------------------------------------------------------------
__global__ __launch_bounds__(256)
void proj_kernel(const float* __restrict__ acc,   // [B*J, C]
                 const float* __restrict__ Wout,  // [C, C]
                 const float* __restrict__ bout,  // [C]
                 float* __restrict__ out)         // [B*J, C]
{
    __shared__ float a_lds[C_];
    __shared__ float partial[4][C_];
    const int bj = blockIdx.x;
    const int t  = threadIdx.x;
    a_lds[t] = acc[(size_t)bj * C_ + t];
    __syncthreads();

    const int wv = t >> 6, ln = t & 63;
    float s0 = 0.0f, s1 = 0.0f, s2 = 0.0f, s3 = 0.0f;
    #pragma unroll 8
    for (int i = 0; i < 64; ++i) {
        const int k = wv * 64 + i;
        const float qv = a_lds[k];
        const float* row = Wout + (size_t)k * C_;
        s0 += qv * row[ln];
        s1 += qv * row[ln + 64];
        s2 += qv * row[ln + 128];
        s3 += qv * row[ln + 192];
    }
    partial[wv][ln]       = s0;
    partial[wv][ln + 64]  = s1;
    partial[wv][ln + 128] = s2;
    partial[wv][ln + 192] = s3;
    __syncthreads();

    float o = bout[t] + partial[0][t] + partial[1][t] + partial[2][t] + partial[3][t];
    out[(size_t)bj * C_ + t] = o;
}

// ---------------------------------------------------------------------------
// Fallback (no/small workspace): monolithic original-layout kernel
// ---------------------------------------------------------------------------
__device__ __forceinline__ float bilin_sample(const float* __restrict__ featc,
                                              float gx, float gy) {
    float ix = (gx + 1.0f) * (0.5f * W_) - 0.5f;
    float iy = (gy + 1.0f) * (0.5f * H_) - 0.5f;
    float x0f = floorf(ix), y0f = floorf(iy);
    int x0 = (int)x0f, y0 = (int)y0f;
    int x1 = x0 + 1,  y1 = y0 + 1;
    float wx1 = ix - x0f, wx0 = 1.0f - wx1;
    float wy1 = iy - y0f, wy0 = 1.0f - wy1;
    bool vx0 = (x0 >= 0) && (x0 < W_);
    bool vx1 = (x1 >= 0) && (x1 < W_);
    bool vy0 = (y0 >= 0) && (y0 < H_);
    bool vy1 = (y1 >= 0) && (y1 < H_);
    int x0c = min(max(x0, 0), W_ - 1), x1c = min(max(x1, 0), W_ - 1);
    int y0c = min(max(y0, 0), H_ - 1), y1c = min(max(y1, 0), H_ - 1);
    float v00 = (vx0 && vy0) ? featc[y0c * W_ + x0c] : 0.0f;
    float v10 = (vx1 && vy0) ? featc[y0c * W_ + x1c] : 0.0f;
    float v01 = (vx0 && vy1) ? featc[y1c * W_ + x0c] : 0.0f;
    float v11 = (vx1 && vy1) ? featc[y1c * W_ + x1c] : 0.0f;
    return v00 * (wx0 * wy0) + v10 * (wx1 * wy0)
         + v01 * (wx0 * wy1) + v11 * (wx1 * wy1);
}

__global__ __launch_bounds__(256)
void msdks_kernel(const float* __restrict__ feat,
                  const float* __restrict__ refpts,
                  const float* __restrict__ Woff,
                  const float* __restrict__ boff,
                  const float* __restrict__ Ww,
                  const float* __restrict__ bw,
                  const float* __restrict__ Wout,
                  const float* __restrict__ bout,
                  float* __restrict__ out)
{
    __shared__ float q_lds[C_];
    __shared__ float off_lds[2 * HP_];
    __shared__ float logit_lds[HP_];
    __shared__ float wgt_lds[HP_];
    __shared__ float gx_lds[HP_];
    __shared__ float gy_lds[HP_];
    __shared__ float acc_lds[C_];

    const int bj = blockIdx.x;
    const int b  = bj / J_;
    const int j  = bj % J_;
    const int c  = threadIdx.x;

    const float rx = refpts[(b * J_ + j) * 2 + 0];
    const float ry = refpts[(b * J_ + j) * 2 + 1];
    const float* featbc = feat + (size_t)(b * C_ + c) * HW_;

    q_lds[c] = bilin_sample(featbc, rx, ry);
    __syncthreads();

    if (c < 64) {
        float s = boff[c];
        for (int k = 0; k < C_; ++k) s += q_lds[k] * Woff[k * 64 + c];
        off_lds[c] = s;
    } else if (c < 96) {
        const int p = c - 64;
        float s = bw[p];
        for (int k = 0; k < C_; ++k) s += q_lds[k] * Ww[k * HP_ + p];
        logit_lds[p] = s;
    }
    __syncthreads();

    if (c < HP_) {
        float l = logit_lds[c];
        float m = l;
        for (int mask = 16; mask; mask >>= 1) m = fmaxf(m, __shfl_xor(m, mask));
        float e = expf(l - m);
        float s = e;
        for (int mask = 16; mask; mask >>= 1) s += __shfl_xor(s, mask);
        wgt_lds[c] = e / s;
        gx_lds[c] = fminf(fmaxf(rx + off_lds[c * 2 + 0], -1.0f), 1.0f);
        gy_lds[c] = fminf(fmaxf(ry + off_lds[c * 2 + 1], -1.0f), 1.0f);
    }
    __syncthreads();

    float acc = 0.0f;
    for (int pp = 0; pp < HP_; ++pp)
        acc += wgt_lds[pp] * bilin_sample(featbc, gx_lds[pp], gy_lds[pp]);
    acc_lds[c] = acc;
    __syncthreads();

    float o = bout[c];
    for (int k = 0; k < C_; ++k) o += acc_lds[k] * Wout[k * C_ + c];
    out[(size_t)(b * J_ + j) * C_ + c] = o;
}

extern "C" void kernel_launch(void* const* d_in, const int* in_sizes, int n_in,
                              void* d_out, int out_size, void* d_ws, size_t ws_size,
                              hipStream_t stream) {
    const float* feat   = (const float*)d_in[0];
    const float* refpts = (const float*)d_in[1];
    const float* Woff   = (const float*)d_in[2];
    const float* boff   = (const float*)d_in[3];
    const float* Ww     = (const float*)d_in[4];
    const float* bw     = (const float*)d_in[5];
    const float* Wout   = (const float*)d_in[6];
    const float* bout   = (const float*)d_in[7];
    float* out = (float*)d_out;

    const size_t n_meta    = (size_t)B_ * J_ * HP_;                // 69632
    const size_t idx_bytes = n_meta * sizeof(int4);
    const size_t w_bytes   = n_meta * sizeof(float4);
    const size_t acc_bytes = (size_t)B_ * J_ * C_ * sizeof(float);

    if (ws_size >= idx_bytes + w_bytes + acc_bytes) {
        char* ws = (char*)d_ws;
        int4*   meta_idx = (int4*)ws;
        float4* meta_w   = (float4*)(ws + idx_bytes);
        float*  acc      = (float*)(ws + idx_bytes + w_bytes);

        pass12_kernel<<<dim3(B_ * J_), dim3(256), 0, stream>>>(
            feat, refpts, Woff, boff, Ww, bw, meta_idx, meta_w);
        gather_kernel<<<dim3(B_ * (C_ / CG_)), dim3(256), 0, stream>>>(
            feat, meta_idx, meta_w, acc);
        proj_kernel<<<dim3(B_ * J_), dim3(256), 0, stream>>>(
            acc, Wout, bout, out);
    } else {
        msdks_kernel<<<dim3(B_ * J_), dim3(256), 0, stream>>>(
            feat, refpts, Woff, boff, Ww, bw, Wout, bout, out);
    }
}

// Round 5
// 162.240 us; speedup vs baseline: 4.4217x; 1.0938x over previous
//
#include <hip/hip_runtime.h>

#define B_  128
#define C_  256
#define H_  64
#define W_  64
#define J_  17
#define HP_ 32          // n_heads * n_points
#define HW_ (H_ * W_)
#define CG_ 2           // channels per gather block (32 KB LDS -> 5 blocks/CU)

// ---------------------------------------------------------------------------
// Pass 1+2: per (b,j) — sample q at ref point, branch-free k-split GEMVs,
// softmax, emit per-(b,j,p) corner metadata.
// ---------------------------------------------------------------------------
__global__ __launch_bounds__(256)
void pass12_kernel(const float* __restrict__ feat,    // [B,C,H,W]
                   const float* __restrict__ refpts,  // [B,J,2]
                   const float* __restrict__ Woff,    // [C,64]
                   const float* __restrict__ boff,    // [64]
                   const float* __restrict__ Ww,      // [C,32]
                   const float* __restrict__ bw,      // [32]
                   int4*  __restrict__ meta_idx,      // [B*J*HP]
                   float4* __restrict__ meta_w)       // [B*J*HP]
{
    __shared__ float q_lds[C_];
    __shared__ float part_off[4][64];
    __shared__ float part_w[8][32];
    __shared__ float off_lds[2 * HP_];
    __shared__ float logit_lds[HP_];

    const int bj = blockIdx.x;
    const int b  = bj / J_;
    const int j  = bj % J_;
    const int c  = threadIdx.x;

    const float rx = refpts[(b * J_ + j) * 2 + 0];
    const float ry = refpts[(b * J_ + j) * 2 + 1];

    // ---- q sample (channel-strided; small volume) ----
    {
        const float* featbc = feat + (size_t)(b * C_ + c) * HW_;
        float ix = (rx + 1.0f) * (0.5f * W_) - 0.5f;
        float iy = (ry + 1.0f) * (0.5f * H_) - 0.5f;
        float x0f = floorf(ix), y0f = floorf(iy);
        int x0 = (int)x0f, y0 = (int)y0f;
        int x1 = x0 + 1,  y1 = y0 + 1;
        float wx1 = ix - x0f, wx0 = 1.0f - wx1;
        float wy1 = iy - y0f, wy0 = 1.0f - wy1;
        bool vx0 = (x0 >= 0) && (x0 < W_);
        bool vx1 = (x1 >= 0) && (x1 < W_);
        bool vy0 = (y0 >= 0) && (y0 < H_);
        bool vy1 = (y1 >= 0) && (y1 < H_);
        int x0c = min(max(x0, 0), W_ - 1), x1c = min(max(x1, 0), W_ - 1);
        int y0c = min(max(y0, 0), H_ - 1), y1c = min(max(y1, 0), H_ - 1);
        float v00 = (vx0 && vy0) ? featbc[y0c * W_ + x0c] : 0.0f;
        float v10 = (vx1 && vy0) ? featbc[y0c * W_ + x1c] : 0.0f;
        float v01 = (vx0 && vy1) ? featbc[y1c * W_ + x0c] : 0.0f;
        float v11 = (vx1 && vy1) ? featbc[y1c * W_ + x1c] : 0.0f;
        q_lds[c] = v00 * (wx0 * wy0) + v10 * (wx1 * wy0)
                 + v01 * (wx0 * wy1) + v11 * (wx1 * wy1);
    }
    __syncthreads();

    // ---- branch-free k-split GEMVs ----
    {
        const int wv = c >> 6, ln = c & 63;
        // offsets: wave wv covers k in [64wv, 64wv+64), lane ln = out col
        float aoff = 0.0f;
        #pragma unroll 8
        for (int i = 0; i < 64; ++i) {
            const int k = wv * 64 + i;
            aoff += q_lds[k] * Woff[k * 64 + ln];
        }
        part_off[wv][ln] = aoff;
        // logits: 8-way k-split (wave wv, half h) x 32 cols
        const int h = ln >> 5, p = ln & 31;
        float aw = 0.0f;
        #pragma unroll 8
        for (int i = 0; i < 32; ++i) {
            const int k = wv * 64 + h * 32 + i;
            aw += q_lds[k] * Ww[k * 32 + p];
        }
        part_w[wv * 2 + h][p] = aw;
    }
    __syncthreads();
    if (c < 64) {
        off_lds[c] = boff[c] + part_off[0][c] + part_off[1][c]
                   + part_off[2][c] + part_off[3][c];
    } else if (c < 96) {
        const int p = c - 64;
        float s = bw[p];
        #pragma unroll
        for (int sidx = 0; sidx < 8; ++sidx) s += part_w[sidx][p];
        logit_lds[p] = s;
    }
    __syncthreads();

    // ---- softmax + grid + corner metadata ----
    if (c < HP_) {
        float l = logit_lds[c];
        float m = l;
        #pragma unroll
        for (int mask = 16; mask >= 1; mask >>= 1) m = fmaxf(m, __shfl_xor(m, mask));
        float e = expf(l - m);
        float s = e;
        #pragma unroll
        for (int mask = 16; mask >= 1; mask >>= 1) s += __shfl_xor(s, mask);
        const float ww = e / s;

        float gx = fminf(fmaxf(rx + off_lds[2 * c + 0], -1.0f), 1.0f);
        float gy = fminf(fmaxf(ry + off_lds[2 * c + 1], -1.0f), 1.0f);
        float ix = (gx + 1.0f) * (0.5f * W_) - 0.5f;
        float iy = (gy + 1.0f) * (0.5f * H_) - 0.5f;
        float x0f = floorf(ix), y0f = floorf(iy);
        int x0 = (int)x0f, y0 = (int)y0f;
        int x1 = x0 + 1,  y1 = y0 + 1;
        float wx1 = ix - x0f, wx0 = 1.0f - wx1;
        float wy1 = iy - y0f, wy0 = 1.0f - wy1;
        float v00 = (float)((x0 >= 0) && (x0 < W_) && (y0 >= 0) && (y0 < H_));
        float v10 = (float)((x1 >= 0) && (x1 < W_) && (y0 >= 0) && (y0 < H_));
        float v01 = (float)((x0 >= 0) && (x0 < W_) && (y1 >= 0) && (y1 < H_));
        float v11 = (float)((x1 >= 0) && (x1 < W_) && (y1 >= 0) && (y1 < H_));
        int x0c = min(max(x0, 0), W_ - 1), x1c = min(max(x1, 0), W_ - 1);
        int y0c = min(max(y0, 0), H_ - 1), y1c = min(max(y1, 0), H_ - 1);
        const int mi = bj * HP_ + c;
        meta_idx[mi] = make_int4(y0c * W_ + x0c, y0c * W_ + x1c,
                                 y1c * W_ + x0c, y1c * W_ + x1c);
        meta_w[mi] = make_float4(ww * wx0 * wy0 * v00, ww * wx1 * wy0 * v10,
                                 ww * wx0 * wy1 * v01, ww * wx1 * wy1 * v11);
    }
}

// ---------------------------------------------------------------------------
// Pass 3: per (b, 2-channel group) — global_load_lds plane staging, meta
// prefetched to registers before the barrier, gather + shuffle reduce.
// ---------------------------------------------------------------------------
__global__ __launch_bounds__(256)
void gather_kernel(const float* __restrict__ feat,      // [B,C,H,W]
                   const int4*  __restrict__ meta_idx,  // [B*J*HP]
                   const float4* __restrict__ meta_w,   // [B*J*HP]
                   float* __restrict__ acc)             // [B,J,C]
{
    __shared__ float plane[CG_ * HW_];   // 32 KB

    const int blk = blockIdx.x;
    const int b   = blk >> 7;       // / (C_/CG_) = /128
    const int cg  = blk & 127;
    const int c0  = cg * CG_;
    const int t   = threadIdx.x;
    const int wv  = t >> 6;         // wave 0..3
    const int ln  = t & 63;

    // ---- stage 2 planes (8192 floats) via global_load_lds width=16 ----
    {
        const char* gsrc = (const char*)(feat + (size_t)(b * C_ + c0) * HW_);
        #pragma unroll
        for (int i = 0; i < 8; ++i) {
            const size_t off = ((size_t)(i * 256 + wv * 64)) * 16;
            __builtin_amdgcn_global_load_lds(
                (const __attribute__((address_space(1))) void*)(gsrc + off + (size_t)ln * 16),
                (__attribute__((address_space(3))) void*)((char*)plane + off),
                16, 0, 0);
        }
    }

    // ---- prefetch meta for all 3 iters while loads drain ----
    const int p    = ln & 31;
    const int half = ln >> 5;
    int4   id_r[3];
    float4 w_r[3];
    #pragma unroll
    for (int iter = 0; iter < 3; ++iter) {
        const int j = iter * 8 + wv * 2 + half;
        if (j < J_) {
            const int mi = (b * J_ + j) * HP_ + p;
            id_r[iter] = meta_idx[mi];
            w_r[iter]  = meta_w[mi];
        } else {
            id_r[iter] = make_int4(0, 0, 0, 0);
            w_r[iter]  = make_float4(0.f, 0.f, 0.f, 0.f);
        }
    }
    __syncthreads();   // drains vmcnt (global_load_lds) + barrier

    #pragma unroll
    for (int iter = 0; iter < 3; ++iter) {
        const int j = iter * 8 + wv * 2 + half;
        const int4   id = id_r[iter];
        const float4 w  = w_r[iter];
        float pj0 = w.x * plane[id.x] + w.y * plane[id.y]
                  + w.z * plane[id.z] + w.w * plane[id.w];
        float pj1 = w.x * plane[HW_ + id.x] + w.y * plane[HW_ + id.y]
                  + w.z * plane[HW_ + id.z] + w.w * plane[HW_ + id.w];
        #pragma unroll
        for (int mask = 16; mask >= 1; mask >>= 1) {
            pj0 += __shfl_xor(pj0, mask);
            pj1 += __shfl_xor(pj1, mask);
        }
        if (j < J_ && p == 0) {
            float2* dst = (float2*)(acc + ((size_t)(b * J_ + j)) * C_ + c0);
            *dst = make_float2(pj0, pj1);
        }
    }
}

// ---------------------------------------------------------------------------
// Pass 4: tiled output projection — 8 bj rows per block, Wout reuse x8.
// ---------------------------------------------------------------------------
#define PROJ_ROWS 8
__global__ __launch_bounds__(256)
void proj_kernel(const float* __restrict__ acc,   // [B*J, C]
                 const float* __restrict__ Wout,  // [C, C]
                 const float* __restrict__ bout,  // [C]
                 float* __restrict__ out)         // [B*J, C]
{
    __shared__ float a_lds[PROJ_ROWS][C_];
    const int bj0 = blockIdx.x * PROJ_ROWS;
    const int t   = threadIdx.x;

    // coalesced load of the 8x256 acc tile
    #pragma unroll
    for (int r = 0; r < PROJ_ROWS; ++r)
        a_lds[r][t] = acc[(size_t)(bj0 + r) * C_ + t];
    __syncthreads();

    const int c = t;   // output column
    float o[PROJ_ROWS];
    const float bb = bout[c];
    #pragma unroll
    for (int r = 0; r < PROJ_ROWS; ++r) o[r] = bb;

    #pragma unroll 4
    for (int k = 0; k < C_; ++k) {
        const float wv = Wout[(size_t)k * C_ + c];
        #pragma unroll
        for (int r = 0; r < PROJ_ROWS; ++r)
            o[r] += a_lds[r][k] * wv;     // same-address LDS broadcast
    }

    #pragma unroll
    for (int r = 0; r < PROJ_ROWS; ++r)
        out[(size_t)(bj0 + r) * C_ + c] = o[r];
}

// ---------------------------------------------------------------------------
// Fallback (no/small workspace): monolithic original-layout kernel
// ---------------------------------------------------------------------------
__device__ __forceinline__ float bilin_sample(const float* __restrict__ featc,
                                              float gx, float gy) {
    float ix = (gx + 1.0f) * (0.5f * W_) - 0.5f;
    float iy = (gy + 1.0f) * (0.5f * H_) - 0.5f;
    float x0f = floorf(ix), y0f = floorf(iy);
    int x0 = (int)x0f, y0 = (int)y0f;
    int x1 = x0 + 1,  y1 = y0 + 1;
    float wx1 = ix - x0f, wx0 = 1.0f - wx1;
    float wy1 = iy - y0f, wy0 = 1.0f - wy1;
    bool vx0 = (x0 >= 0) && (x0 < W_);
    bool vx1 = (x1 >= 0) && (x1 < W_);
    bool vy0 = (y0 >= 0) && (y0 < H_);
    bool vy1 = (y1 >= 0) && (y1 < H_);
    int x0c = min(max(x0, 0), W_ - 1), x1c = min(max(x1, 0), W_ - 1);
    int y0c = min(max(y0, 0), H_ - 1), y1c = min(max(y1, 0), H_ - 1);
    float v00 = (vx0 && vy0) ? featc[y0c * W_ + x0c] : 0.0f;
    float v10 = (vx1 && vy0) ? featc[y0c * W_ + x1c] : 0.0f;
    float v01 = (vx0 && vy1) ? featc[y1c * W_ + x0c] : 0.0f;
    float v11 = (vx1 && vy1) ? featc[y1c * W_ + x1c] : 0.0f;
    return v00 * (wx0 * wy0) + v10 * (wx1 * wy0)
         + v01 * (wx0 * wy1) + v11 * (wx1 * wy1);
}

__global__ __launch_bounds__(256)
void msdks_kernel(const float* __restrict__ feat,
                  const float* __restrict__ refpts,
                  const float* __restrict__ Woff,
                  const float* __restrict__ boff,
                  const float* __restrict__ Ww,
                  const float* __restrict__ bw,
                  const float* __restrict__ Wout,
                  const float* __restrict__ bout,
                  float* __restrict__ out)
{
    __shared__ float q_lds[C_];
    __shared__ float off_lds[2 * HP_];
    __shared__ float logit_lds[HP_];
    __shared__ float wgt_lds[HP_];
    __shared__ float gx_lds[HP_];
    __shared__ float gy_lds[HP_];
    __shared__ float acc_lds[C_];

    const int bj = blockIdx.x;
    const int b  = bj / J_;
    const int j  = bj % J_;
    const int c  = threadIdx.x;

    const float rx = refpts[(b * J_ + j) * 2 + 0];
    const float ry = refpts[(b * J_ + j) * 2 + 1];
    const float* featbc = feat + (size_t)(b * C_ + c) * HW_;

    q_lds[c] = bilin_sample(featbc, rx, ry);
    __syncthreads();

    if (c < 64) {
        float s = boff[c];
        for (int k = 0; k < C_; ++k) s += q_lds[k] * Woff[k * 64 + c];
        off_lds[c] = s;
    } else if (c < 96) {
        const int p = c - 64;
        float s = bw[p];
        for (int k = 0; k < C_; ++k) s += q_lds[k] * Ww[k * HP_ + p];
        logit_lds[p] = s;
    }
    __syncthreads();

    if (c < HP_) {
        float l = logit_lds[c];
        float m = l;
        for (int mask = 16; mask; mask >>= 1) m = fmaxf(m, __shfl_xor(m, mask));
        float e = expf(l - m);
        float s = e;
        for (int mask = 16; mask; mask >>= 1) s += __shfl_xor(s, mask);
        wgt_lds[c] = e / s;
        gx_lds[c] = fminf(fmaxf(rx + off_lds[c * 2 + 0], -1.0f), 1.0f);
        gy_lds[c] = fminf(fmaxf(ry + off_lds[c * 2 + 1], -1.0f), 1.0f);
    }
    __syncthreads();

    float acc = 0.0f;
    for (int pp = 0; pp < HP_; ++pp)
        acc += wgt_lds[pp] * bilin_sample(featbc, gx_lds[pp], gy_lds[pp]);
    acc_lds[c] = acc;
    __syncthreads();

    float o = bout[c];
    for (int k = 0; k < C_; ++k) o += acc_lds[k] * Wout[k * C_ + c];
    out[(size_t)(b * J_ + j) * C_ + c] = o;
}

extern "C" void kernel_launch(void* const* d_in, const int* in_sizes, int n_in,
                              void* d_out, int out_size, void* d_ws, size_t ws_size,
                              hipStream_t stream) {
    const float* feat   = (const float*)d_in[0];
    const float* refpts = (const float*)d_in[1];
    const float* Woff   = (const float*)d_in[2];
    const float* boff   = (const float*)d_in[3];
    const float* Ww     = (const float*)d_in[4];
    const float* bw     = (const float*)d_in[5];
    const float* Wout   = (const float*)d_in[6];
    const float* bout   = (const float*)d_in[7];
    float* out = (float*)d_out;

    const size_t n_meta    = (size_t)B_ * J_ * HP_;                // 69632
    const size_t idx_bytes = n_meta * sizeof(int4);
    const size_t w_bytes   = n_meta * sizeof(float4);
    const size_t acc_bytes = (size_t)B_ * J_ * C_ * sizeof(float);

    if (ws_size >= idx_bytes + w_bytes + acc_bytes) {
        char* ws = (char*)d_ws;
        int4*   meta_idx = (int4*)ws;
        float4* meta_w   = (float4*)(ws + idx_bytes);
        float*  acc      = (float*)(ws + idx_bytes + w_bytes);

        pass12_kernel<<<dim3(B_ * J_), dim3(256), 0, stream>>>(
            feat, refpts, Woff, boff, Ww, bw, meta_idx, meta_w);
        gather_kernel<<<dim3(B_ * (C_ / CG_)), dim3(256), 0, stream>>>(
            feat, meta_idx, meta_w, acc);
        proj_kernel<<<dim3((B_ * J_) / PROJ_ROWS), dim3(256), 0, stream>>>(
            acc, Wout, bout, out);
    } else {
        msdks_kernel<<<dim3(B_ * J_), dim3(256), 0, stream>>>(
            feat, refpts, Woff, boff, Ww, bw, Wout, bout, out);
    }
}

// Round 6
// 155.581 us; speedup vs baseline: 4.6110x; 1.0428x over previous
//
#include <hip/hip_runtime.h>

#define B_  128
#define C_  256
#define H_  64
#define W_  64
#define J_  17
#define HP_ 32          // n_heads * n_points
#define HW_ (H_ * W_)
#define CG_ 4           // channels per gather block (64 KB LDS -> 2 blocks/CU)

// ---------------------------------------------------------------------------
// Pass 1+2: per (b,j) — sample q at ref point, branch-free k-split GEMVs,
// softmax, emit per-(b,j,p) corner metadata.
// ---------------------------------------------------------------------------
__global__ __launch_bounds__(256)
void pass12_kernel(const float* __restrict__ feat,    // [B,C,H,W]
                   const float* __restrict__ refpts,  // [B,J,2]
                   const float* __restrict__ Woff,    // [C,64]
                   const float* __restrict__ boff,    // [64]
                   const float* __restrict__ Ww,      // [C,32]
                   const float* __restrict__ bw,      // [32]
                   int4*  __restrict__ meta_idx,      // [B*J*HP]
                   float4* __restrict__ meta_w)       // [B*J*HP]
{
    __shared__ float q_lds[C_];
    __shared__ float part_off[4][64];
    __shared__ float part_w[8][32];
    __shared__ float off_lds[2 * HP_];
    __shared__ float logit_lds[HP_];

    const int bj = blockIdx.x;
    const int b  = bj / J_;
    const int j  = bj % J_;
    const int c  = threadIdx.x;

    const float rx = refpts[(b * J_ + j) * 2 + 0];
    const float ry = refpts[(b * J_ + j) * 2 + 1];

    // ---- q sample (channel-strided; random-line bound) ----
    {
        const float* featbc = feat + (size_t)(b * C_ + c) * HW_;
        float ix = (rx + 1.0f) * (0.5f * W_) - 0.5f;
        float iy = (ry + 1.0f) * (0.5f * H_) - 0.5f;
        float x0f = floorf(ix), y0f = floorf(iy);
        int x0 = (int)x0f, y0 = (int)y0f;
        int x1 = x0 + 1,  y1 = y0 + 1;
        float wx1 = ix - x0f, wx0 = 1.0f - wx1;
        float wy1 = iy - y0f, wy0 = 1.0f - wy1;
        bool vx0 = (x0 >= 0) && (x0 < W_);
        bool vx1 = (x1 >= 0) && (x1 < W_);
        bool vy0 = (y0 >= 0) && (y0 < H_);
        bool vy1 = (y1 >= 0) && (y1 < H_);
        int x0c = min(max(x0, 0), W_ - 1), x1c = min(max(x1, 0), W_ - 1);
        int y0c = min(max(y0, 0), H_ - 1), y1c = min(max(y1, 0), H_ - 1);
        float v00 = (vx0 && vy0) ? featbc[y0c * W_ + x0c] : 0.0f;
        float v10 = (vx1 && vy0) ? featbc[y0c * W_ + x1c] : 0.0f;
        float v01 = (vx0 && vy1) ? featbc[y1c * W_ + x0c] : 0.0f;
        float v11 = (vx1 && vy1) ? featbc[y1c * W_ + x1c] : 0.0f;
        q_lds[c] = v00 * (wx0 * wy0) + v10 * (wx1 * wy0)
                 + v01 * (wx0 * wy1) + v11 * (wx1 * wy1);
    }
    __syncthreads();

    // ---- branch-free k-split GEMVs ----
    {
        const int wv = c >> 6, ln = c & 63;
        float aoff = 0.0f;
        #pragma unroll 8
        for (int i = 0; i < 64; ++i) {
            const int k = wv * 64 + i;
            aoff += q_lds[k] * Woff[k * 64 + ln];
        }
        part_off[wv][ln] = aoff;
        const int h = ln >> 5, p = ln & 31;
        float aw = 0.0f;
        #pragma unroll 8
        for (int i = 0; i < 32; ++i) {
            const int k = wv * 64 + h * 32 + i;
            aw += q_lds[k] * Ww[k * 32 + p];
        }
        part_w[wv * 2 + h][p] = aw;
    }
    __syncthreads();
    if (c < 64) {
        off_lds[c] = boff[c] + part_off[0][c] + part_off[1][c]
                   + part_off[2][c] + part_off[3][c];
    } else if (c < 96) {
        const int p = c - 64;
        float s = bw[p];
        #pragma unroll
        for (int sidx = 0; sidx < 8; ++sidx) s += part_w[sidx][p];
        logit_lds[p] = s;
    }
    __syncthreads();

    // ---- softmax + grid + corner metadata ----
    if (c < HP_) {
        float l = logit_lds[c];
        float m = l;
        #pragma unroll
        for (int mask = 16; mask >= 1; mask >>= 1) m = fmaxf(m, __shfl_xor(m, mask));
        float e = expf(l - m);
        float s = e;
        #pragma unroll
        for (int mask = 16; mask >= 1; mask >>= 1) s += __shfl_xor(s, mask);
        const float ww = e / s;

        float gx = fminf(fmaxf(rx + off_lds[2 * c + 0], -1.0f), 1.0f);
        float gy = fminf(fmaxf(ry + off_lds[2 * c + 1], -1.0f), 1.0f);
        float ix = (gx + 1.0f) * (0.5f * W_) - 0.5f;
        float iy = (gy + 1.0f) * (0.5f * H_) - 0.5f;
        float x0f = floorf(ix), y0f = floorf(iy);
        int x0 = (int)x0f, y0 = (int)y0f;
        int x1 = x0 + 1,  y1 = y0 + 1;
        float wx1 = ix - x0f, wx0 = 1.0f - wx1;
        float wy1 = iy - y0f, wy0 = 1.0f - wy1;
        float v00 = (float)((x0 >= 0) && (x0 < W_) && (y0 >= 0) && (y0 < H_));
        float v10 = (float)((x1 >= 0) && (x1 < W_) && (y0 >= 0) && (y0 < H_));
        float v01 = (float)((x0 >= 0) && (x0 < W_) && (y1 >= 0) && (y1 < H_));
        float v11 = (float)((x1 >= 0) && (x1 < W_) && (y1 >= 0) && (y1 < H_));
        int x0c = min(max(x0, 0), W_ - 1), x1c = min(max(x1, 0), W_ - 1);
        int y0c = min(max(y0, 0), H_ - 1), y1c = min(max(y1, 0), H_ - 1);
        const int mi = bj * HP_ + c;
        meta_idx[mi] = make_int4(y0c * W_ + x0c, y0c * W_ + x1c,
                                 y1c * W_ + x0c, y1c * W_ + x1c);
        meta_w[mi] = make_float4(ww * wx0 * wy0 * v00, ww * wx1 * wy0 * v10,
                                 ww * wx0 * wy1 * v01, ww * wx1 * wy1 * v11);
    }
}

// ---------------------------------------------------------------------------
// Pass 3: per (b, 4-channel group), 512 threads — global_load_lds staging of
// 4 planes (64 KB), meta prefetched to registers, gather + shuffle reduce.
// ---------------------------------------------------------------------------
__global__ __launch_bounds__(512)
void gather_kernel(const float* __restrict__ feat,      // [B,C,H,W]
                   const int4*  __restrict__ meta_idx,  // [B*J*HP]
                   const float4* __restrict__ meta_w,   // [B*J*HP]
                   float* __restrict__ acc)             // [B,J,C]
{
    __shared__ float plane[CG_ * HW_];   // 64 KB

    const int blk = blockIdx.x;
    const int b   = blk >> 6;       // / (C_/CG_) = /64
    const int cg  = blk & 63;
    const int c0  = cg * CG_;
    const int t   = threadIdx.x;
    const int wv  = t >> 6;         // wave 0..7
    const int ln  = t & 63;

    // ---- stage 4 planes (16384 floats = 64 KB) via global_load_lds w=16 ----
    {
        const char* gsrc = (const char*)(feat + (size_t)(b * C_ + c0) * HW_);
        #pragma unroll
        for (int i = 0; i < 8; ++i) {
            const size_t off = ((size_t)(i * 512 + wv * 64)) * 16;
            __builtin_amdgcn_global_load_lds(
                (const __attribute__((address_space(1))) void*)(gsrc + off + (size_t)ln * 16),
                (__attribute__((address_space(3))) void*)((char*)plane + off),
                16, 0, 0);
        }
    }

    // ---- prefetch meta for both iters while loads drain ----
    const int p    = ln & 31;
    const int half = ln >> 5;
    int4   id_r[2];
    float4 w_r[2];
    #pragma unroll
    for (int iter = 0; iter < 2; ++iter) {
        const int j = iter * 16 + wv * 2 + half;
        if (j < J_) {
            const int mi = (b * J_ + j) * HP_ + p;
            id_r[iter] = meta_idx[mi];
            w_r[iter]  = meta_w[mi];
        } else {
            id_r[iter] = make_int4(0, 0, 0, 0);
            w_r[iter]  = make_float4(0.f, 0.f, 0.f, 0.f);
        }
    }
    __syncthreads();   // drains vmcnt (global_load_lds) + barrier

    #pragma unroll
    for (int iter = 0; iter < 2; ++iter) {
        const int j = iter * 16 + wv * 2 + half;
        const int4   id = id_r[iter];
        const float4 w  = w_r[iter];
        float pj0 = w.x * plane[0 * HW_ + id.x] + w.y * plane[0 * HW_ + id.y]
                  + w.z * plane[0 * HW_ + id.z] + w.w * plane[0 * HW_ + id.w];
        float pj1 = w.x * plane[1 * HW_ + id.x] + w.y * plane[1 * HW_ + id.y]
                  + w.z * plane[1 * HW_ + id.z] + w.w * plane[1 * HW_ + id.w];
        float pj2 = w.x * plane[2 * HW_ + id.x] + w.y * plane[2 * HW_ + id.y]
                  + w.z * plane[2 * HW_ + id.z] + w.w * plane[2 * HW_ + id.w];
        float pj3 = w.x * plane[3 * HW_ + id.x] + w.y * plane[3 * HW_ + id.y]
                  + w.z * plane[3 * HW_ + id.z] + w.w * plane[3 * HW_ + id.w];
        #pragma unroll
        for (int mask = 16; mask >= 1; mask >>= 1) {
            pj0 += __shfl_xor(pj0, mask);
            pj1 += __shfl_xor(pj1, mask);
            pj2 += __shfl_xor(pj2, mask);
            pj3 += __shfl_xor(pj3, mask);
        }
        if (j < J_ && p == 0) {
            float4* dst = (float4*)(acc + ((size_t)(b * J_ + j)) * C_ + c0);
            *dst = make_float4(pj0, pj1, pj2, pj3);
        }
    }
}

// ---------------------------------------------------------------------------
// Pass 4: tiled output projection — 8 bj rows per block, Wout reuse x8.
// ---------------------------------------------------------------------------
#define PROJ_ROWS 8
__global__ __launch_bounds__(256)
void proj_kernel(const float* __restrict__ acc,   // [B*J, C]
                 const float* __restrict__ Wout,  // [C, C]
                 const float* __restrict__ bout,  // [C]
                 float* __restrict__ out)         // [B*J, C]
{
    __shared__ float a_lds[PROJ_ROWS][C_];
    const int bj0 = blockIdx.x * PROJ_ROWS;
    const int t   = threadIdx.x;

    #pragma unroll
    for (int r = 0; r < PROJ_ROWS; ++r)
        a_lds[r][t] = acc[(size_t)(bj0 + r) * C_ + t];
    __syncthreads();

    const int c = t;
    float o[PROJ_ROWS];
    const float bb = bout[c];
    #pragma unroll
    for (int r = 0; r < PROJ_ROWS; ++r) o[r] = bb;

    #pragma unroll 4
    for (int k = 0; k < C_; ++k) {
        const float wv = Wout[(size_t)k * C_ + c];
        #pragma unroll
        for (int r = 0; r < PROJ_ROWS; ++r)
            o[r] += a_lds[r][k] * wv;
    }

    #pragma unroll
    for (int r = 0; r < PROJ_ROWS; ++r)
        out[(size_t)(bj0 + r) * C_ + c] = o[r];
}

// ---------------------------------------------------------------------------
// Fallback (no/small workspace): monolithic original-layout kernel
// ---------------------------------------------------------------------------
__device__ __forceinline__ float bilin_sample(const float* __restrict__ featc,
                                              float gx, float gy) {
    float ix = (gx + 1.0f) * (0.5f * W_) - 0.5f;
    float iy = (gy + 1.0f) * (0.5f * H_) - 0.5f;
    float x0f = floorf(ix), y0f = floorf(iy);
    int x0 = (int)x0f, y0 = (int)y0f;
    int x1 = x0 + 1,  y1 = y0 + 1;
    float wx1 = ix - x0f, wx0 = 1.0f - wx1;
    float wy1 = iy - y0f, wy0 = 1.0f - wy1;
    bool vx0 = (x0 >= 0) && (x0 < W_);
    bool vx1 = (x1 >= 0) && (x1 < W_);
    bool vy0 = (y0 >= 0) && (y0 < H_);
    bool vy1 = (y1 >= 0) && (y1 < H_);
    int x0c = min(max(x0, 0), W_ - 1), x1c = min(max(x1, 0), W_ - 1);
    int y0c = min(max(y0, 0), H_ - 1), y1c = min(max(y1, 0), H_ - 1);
    float v00 = (vx0 && vy0) ? featc[y0c * W_ + x0c] : 0.0f;
    float v10 = (vx1 && vy0) ? featc[y0c * W_ + x1c] : 0.0f;
    float v01 = (vx0 && vy1) ? featc[y1c * W_ + x0c] : 0.0f;
    float v11 = (vx1 && vy1) ? featc[y1c * W_ + x1c] : 0.0f;
    return v00 * (wx0 * wy0) + v10 * (wx1 * wy0)
         + v01 * (wx0 * wy1) + v11 * (wx1 * wy1);
}

__global__ __launch_bounds__(256)
void msdks_kernel(const float* __restrict__ feat,
                  const float* __restrict__ refpts,
                  const float* __restrict__ Woff,
                  const float* __restrict__ boff,
                  const float* __restrict__ Ww,
                  const float* __restrict__ bw,
                  const float* __restrict__ Wout,
                  const float* __restrict__ bout,
                  float* __restrict__ out)
{
    __shared__ float q_lds[C_];
    __shared__ float off_lds[2 * HP_];
    __shared__ float logit_lds[HP_];
    __shared__ float wgt_lds[HP_];
    __shared__ float gx_lds[HP_];
    __shared__ float gy_lds[HP_];
    __shared__ float acc_lds[C_];

    const int bj = blockIdx.x;
    const int b  = bj / J_;
    const int j  = bj % J_;
    const int c  = threadIdx.x;

    const float rx = refpts[(b * J_ + j) * 2 + 0];
    const float ry = refpts[(b * J_ + j) * 2 + 1];
    const float* featbc = feat + (size_t)(b * C_ + c) * HW_;

    q_lds[c] = bilin_sample(featbc, rx, ry);
    __syncthreads();

    if (c < 64) {
        float s = boff[c];
        for (int k = 0; k < C_; ++k) s += q_lds[k] * Woff[k * 64 + c];
        off_lds[c] = s;
    } else if (c < 96) {
        const int p = c - 64;
        float s = bw[p];
        for (int k = 0; k < C_; ++k) s += q_lds[k] * Ww[k * HP_ + p];
        logit_lds[p] = s;
    }
    __syncthreads();

    if (c < HP_) {
        float l = logit_lds[c];
        float m = l;
        for (int mask = 16; mask; mask >>= 1) m = fmaxf(m, __shfl_xor(m, mask));
        float e = expf(l - m);
        float s = e;
        for (int mask = 16; mask; mask >>= 1) s += __shfl_xor(s, mask);
        wgt_lds[c] = e / s;
        gx_lds[c] = fminf(fmaxf(rx + off_lds[c * 2 + 0], -1.0f), 1.0f);
        gy_lds[c] = fminf(fmaxf(ry + off_lds[c * 2 + 1], -1.0f), 1.0f);
    }
    __syncthreads();

    float acc = 0.0f;
    for (int pp = 0; pp < HP_; ++pp)
        acc += wgt_lds[pp] * bilin_sample(featbc, gx_lds[pp], gy_lds[pp]);
    acc_lds[c] = acc;
    __syncthreads();

    float o = bout[c];
    for (int k = 0; k < C_; ++k) o += acc_lds[k] * Wout[k * C_ + c];
    out[(size_t)(b * J_ + j) * C_ + c] = o;
}

extern "C" void kernel_launch(void* const* d_in, const int* in_sizes, int n_in,
                              void* d_out, int out_size, void* d_ws, size_t ws_size,
                              hipStream_t stream) {
    const float* feat   = (const float*)d_in[0];
    const float* refpts = (const float*)d_in[1];
    const float* Woff   = (const float*)d_in[2];
    const float* boff   = (const float*)d_in[3];
    const float* Ww     = (const float*)d_in[4];
    const float* bw     = (const float*)d_in[5];
    const float* Wout   = (const float*)d_in[6];
    const float* bout   = (const float*)d_in[7];
    float* out = (float*)d_out;

    const size_t n_meta    = (size_t)B_ * J_ * HP_;                // 69632
    const size_t idx_bytes = n_meta * sizeof(int4);
    const size_t w_bytes   = n_meta * sizeof(float4);
    const size_t acc_bytes = (size_t)B_ * J_ * C_ * sizeof(float);

    if (ws_size >= idx_bytes + w_bytes + acc_bytes) {
        char* ws = (char*)d_ws;
        int4*   meta_idx = (int4*)ws;
        float4* meta_w   = (float4*)(ws + idx_bytes);
        float*  acc      = (float*)(ws + idx_bytes + w_bytes);

        pass12_kernel<<<dim3(B_ * J_), dim3(256), 0, stream>>>(
            feat, refpts, Woff, boff, Ww, bw, meta_idx, meta_w);
        gather_kernel<<<dim3(B_ * (C_ / CG_)), dim3(512), 0, stream>>>(
            feat, meta_idx, meta_w, acc);
        proj_kernel<<<dim3((B_ * J_) / PROJ_ROWS), dim3(256), 0, stream>>>(
            acc, Wout, bout, out);
    } else {
        msdks_kernel<<<dim3(B_ * J_), dim3(256), 0, stream>>>(
            feat, refpts, Woff, boff, Ww, bw, Wout, bout, out);
    }
}